// Round 2
// baseline (9992.033 us; speedup 1.0000x reference)
//
#include <hip/hip_runtime.h>
#include <math.h>

#define T_STEPS 1024
#define NB 64        // batch
#define NH 512       // hidden
#define NI 256       // input
#define GSIZE 8      // WGs per batch-group (hidden slices)
#define NGRP 8       // batch groups
#define BPG 8        // batches per group
#define HPW 64       // hidden columns per WG

// d_ws layout
#define WS_YBUF_OFF  4096                      // double-buffered y: 2*64*512 f32
#define WS_INIT_BYTES (WS_YBUF_OFF + NB*NH*4)  // counters + y buffer 0 only

// ---------------------------------------------------------------------------
// Kernel 1: ext[t,b,h] = inputs[t,b,:] @ W_ih[:,h] + b_ih[h], written to d_out.
// ---------------------------------------------------------------------------
__global__ __launch_bounds__(256) void ext_gemm_kernel(
    const float* __restrict__ inputs, const float* __restrict__ W_ih,
    const float* __restrict__ b_ih, float* __restrict__ out)
{
    __shared__ float Wt[NI * 64];   // [i][h], 64 KiB
    const int tid    = threadIdx.x;
    const int hgrp   = blockIdx.x & 7;
    const int rowgrp = blockIdx.x >> 3;
    const int hbase  = hgrp * 64;
    const long rowbase = (long)rowgrp * 512;

    for (int idx = tid; idx < NI * 64; idx += 256) {
        int i  = idx >> 6;
        int hh = idx & 63;
        Wt[idx] = W_ih[(size_t)i * NH + hbase + hh];
    }
    const int hq = tid & 15;   // h quad -> h = hq*4 .. hq*4+3
    const int r  = tid >> 4;   // row within 16-row chunk
    const float4 bias = *(const float4*)&b_ih[hbase + hq * 4];
    __syncthreads();

    for (int rc = 0; rc < 32; ++rc) {
        const long row = rowbase + rc * 16 + r;
        const float* __restrict__ inrow = inputs + row * NI;
        float ax = 0.f, ay = 0.f, az = 0.f, aw = 0.f;
        #pragma unroll 4
        for (int i = 0; i < NI; i += 4) {
            const float4 a  = *(const float4*)(inrow + i);
            const float4 w0 = *(const float4*)&Wt[(i + 0) * 64 + hq * 4];
            const float4 w1 = *(const float4*)&Wt[(i + 1) * 64 + hq * 4];
            const float4 w2 = *(const float4*)&Wt[(i + 2) * 64 + hq * 4];
            const float4 w3 = *(const float4*)&Wt[(i + 3) * 64 + hq * 4];
            ax += a.x * w0.x + a.y * w1.x + a.z * w2.x + a.w * w3.x;
            ay += a.x * w0.y + a.y * w1.y + a.z * w2.y + a.w * w3.y;
            az += a.x * w0.z + a.y * w1.z + a.z * w2.z + a.w * w3.z;
            aw += a.x * w0.w + a.y * w1.w + a.z * w2.w + a.w * w3.w;
        }
        float4 o = make_float4(ax + bias.x, ay + bias.y, az + bias.z, aw + bias.w);
        *(float4*)&out[row * NH + hbase + hq * 4] = o;
    }
}

__device__ __forceinline__ float tanh_fast(float x) {
    // tanh(x) = (1 - e^{-2x}) / (1 + e^{-2x}); clamp avoids overflow, tanh
    // saturates to +-1 well before |x|=15 in f32.
    x = fminf(15.f, fmaxf(-15.f, x));
    const float ex = __expf(-2.f * x);
    return __fdividef(1.f - ex, 1.f + ex);
}

// ---------------------------------------------------------------------------
// Kernel 2: persistent recurrent scan. 64 WGs x 512 threads.
//   grp = bid & 7 (batch group; same XCD under round-robin dispatch — perf
//   heuristic only, correctness uses agent-scope release/acquire).
// Weights register-resident (64 f32/thread, __launch_bounds__(512,2) gives a
// 256-VGPR budget so they cannot spill). y is exchanged through global: each
// step writes y_t, release-signals a per-group counter, relaxed-polls, then
// one acquire fence. y reads are wave-uniform float4 broadcasts from L2/L3.
// ---------------------------------------------------------------------------
__global__ __launch_bounds__(512, 2) void horn_recurrent_kernel(
    const float* __restrict__ W_hh, const float* __restrict__ b_hh,
    const float* __restrict__ alpha, const float* __restrict__ omega,
    const float* __restrict__ gamma, const float* __restrict__ v,
    float* __restrict__ out, float* __restrict__ ybuf,
    unsigned* __restrict__ counters)
{
    __shared__ float part[GSIZE][BPG][HPW];      // 16 KiB

    const int tid   = threadIdx.x;
    const int grp   = blockIdx.x & 7;    // batch group
    const int hgrp  = blockIdx.x >> 3;   // hidden slice
    const int bbase = grp * BPG;
    const int hbase = hgrp * HPW;

    // GEMM mapping
    const int kgrp = tid >> 6;   // 0..7 (k-split)
    const int hk   = tid & 63;   // h within slice
    // update mapping
    const int b2 = tid >> 6;     // 0..7
    const int h2 = tid & 63;
    const int hg = hbase + h2;   // global h

    // per-thread W_hh slice: W_hh[kgrp*64 + kk][hbase + hk], kk = 0..63
    // (coalesced: consecutive lanes -> consecutive h)
    float wreg[64];
    {
        const float* wp = W_hh + (size_t)(kgrp * 64) * NH + hbase + hk;
        #pragma unroll
        for (int kk = 0; kk < 64; ++kk) wreg[kk] = wp[(size_t)kk * NH];
    }
    const float bhh_r = b_hh[hg];
    const float al_r  = alpha[hg];
    const float omv   = omega[hg];
    const float om2_r = omv * omv;
    const float g2_r  = 2.0f * gamma[hg];
    const float v_r   = v[hg];
    const float gain  = 0.04419417382415922f;   // 1/sqrt(512)
    const float hdt   = 0.1f;

    unsigned* cnt = counters + grp * 64;   // 256B spacing per group

    float x = 0.f, y = 0.f;

    for (int t = 0; t < T_STEPS; ++t) {
        // external input for this (b,h) — independent of y, issue early
        const size_t eidx = ((size_t)t * NB + bbase + b2) * NH + hg;
        const float e = out[eidx];

        // GEMM: acc[b] = sum over this thread's 64 k of y[b][k]*W[k][h].
        // y read directly from global as wave-uniform float4 broadcasts.
        const float* __restrict__ ysrc =
            ybuf + (size_t)(t & 1) * NB * NH + (size_t)bbase * NH + kgrp * 64;
        float acc[8];
        #pragma unroll
        for (int b = 0; b < 8; ++b) acc[b] = 0.f;
        #pragma unroll
        for (int b = 0; b < 8; ++b) {
            const float* __restrict__ yb = ysrc + b * NH;
            #pragma unroll
            for (int q = 0; q < 16; ++q) {
                const float4 yv = *(const float4*)(yb + q * 4);
                acc[b] += yv.x * wreg[q * 4 + 0] + yv.y * wreg[q * 4 + 1]
                        + yv.z * wreg[q * 4 + 2] + yv.w * wreg[q * 4 + 3];
            }
        }
        #pragma unroll
        for (int b = 0; b < 8; ++b) part[kgrp][b][hk] = acc[b];
        __syncthreads();

        // reduce over k-groups + bias
        float rec = bhh_r;
        #pragma unroll
        for (int g = 0; g < GSIZE; ++g) rec += part[g][b2][h2];

        // elementwise update
        const float inp  = e + gain * (rec + v_r * x);
        const float ynew = y + hdt * (al_r * tanh_fast(inp) - om2_r * x - g2_r * y);
        const float xnew = x + hdt * ynew;
        x = xnew; y = ynew;

        // y_t must be visible to sibling WGs before the signal
        ybuf[(size_t)((t + 1) & 1) * NB * NH + (size_t)(bbase + b2) * NH + hg] = ynew;

        if (t == T_STEPS - 1) {
            out[eidx] = xnew;
            break;
        }

        // ---- group barrier ----
        asm volatile("s_waitcnt vmcnt(0)" ::: "memory");  // my y store is in L2
        __syncthreads();                                  // whole WG's stores are
        if (tid == 0) {
            // release: wbL2 once, then signal
            __hip_atomic_fetch_add(cnt, 1u, __ATOMIC_RELEASE, __HIP_MEMORY_SCOPE_AGENT);
            const unsigned target = (unsigned)GSIZE * (unsigned)(t + 1);
            while (__hip_atomic_load(cnt, __ATOMIC_RELAXED, __HIP_MEMORY_SCOPE_AGENT) < target) {
                __builtin_amdgcn_s_sleep(1);
            }
            __builtin_amdgcn_fence(__ATOMIC_ACQUIRE, "agent");  // one L2 inv
        }
        __syncthreads();

        // x output is not read by anyone — store after the signal, off the
        // critical path (next step's release waitcnt covers it).
        out[eidx] = xnew;
    }
}

// ---------------------------------------------------------------------------
extern "C" void kernel_launch(void* const* d_in, const int* in_sizes, int n_in,
                              void* d_out, int out_size, void* d_ws, size_t ws_size,
                              hipStream_t stream) {
    const float* inputs = (const float*)d_in[0];
    const float* W_ih   = (const float*)d_in[1];
    const float* b_ih   = (const float*)d_in[2];
    const float* W_hh   = (const float*)d_in[3];
    const float* b_hh   = (const float*)d_in[4];
    const float* alpha  = (const float*)d_in[5];
    const float* omega  = (const float*)d_in[6];
    const float* gamma  = (const float*)d_in[7];
    const float* v      = (const float*)d_in[8];
    float* out = (float*)d_out;

    unsigned* counters = (unsigned*)d_ws;
    float* ybuf = (float*)((char*)d_ws + WS_YBUF_OFF);

    // zero barrier counters + y buffer 0 (d_ws is re-poisoned every launch)
    hipMemsetAsync(d_ws, 0, WS_INIT_BYTES, stream);

    // ext = inputs @ W_ih + b_ih, written into d_out (overwritten step-by-step)
    ext_gemm_kernel<<<dim3(1024), dim3(256), 0, stream>>>(inputs, W_ih, b_ih, out);

    // sequential scan, persistent kernel
    horn_recurrent_kernel<<<dim3(64), dim3(512), 0, stream>>>(
        W_hh, b_hh, alpha, omega, gamma, v, out, ybuf, counters);
}

// Round 3
// 5281.384 us; speedup vs baseline: 1.8919x; 1.8919x over previous
//
#include <hip/hip_runtime.h>
#include <math.h>

#define T_STEPS 1024
#define NB 64        // batch
#define NH 512       // hidden
#define NI 256       // input
#define GSIZE 8      // WGs per batch-group (hidden slices)
#define NGRP 16      // batch groups
#define BPG 4        // batches per group
#define HPW 64       // hidden columns per WG

// d_ws layout
#define WS_YBUF_OFF  4096                      // double-buffered y: 2*64*512 f32
#define WS_INIT_BYTES (WS_YBUF_OFF + NB*NH*4)  // counters + y buffer 0 only

// ---------------------------------------------------------------------------
// Kernel 1: ext[t,b,h] = inputs[t,b,:] @ W_ih[:,h] + b_ih[h], written to d_out.
// ---------------------------------------------------------------------------
__global__ __launch_bounds__(256) void ext_gemm_kernel(
    const float* __restrict__ inputs, const float* __restrict__ W_ih,
    const float* __restrict__ b_ih, float* __restrict__ out)
{
    __shared__ float Wt[NI * 64];   // [i][h], 64 KiB
    const int tid    = threadIdx.x;
    const int hgrp   = blockIdx.x & 7;
    const int rowgrp = blockIdx.x >> 3;
    const int hbase  = hgrp * 64;
    const long rowbase = (long)rowgrp * 512;

    for (int idx = tid; idx < NI * 64; idx += 256) {
        int i  = idx >> 6;
        int hh = idx & 63;
        Wt[idx] = W_ih[(size_t)i * NH + hbase + hh];
    }
    const int hq = tid & 15;   // h quad -> h = hq*4 .. hq*4+3
    const int r  = tid >> 4;   // row within 16-row chunk
    const float4 bias = *(const float4*)&b_ih[hbase + hq * 4];
    __syncthreads();

    for (int rc = 0; rc < 32; ++rc) {
        const long row = rowbase + rc * 16 + r;
        const float* __restrict__ inrow = inputs + row * NI;
        float ax = 0.f, ay = 0.f, az = 0.f, aw = 0.f;
        #pragma unroll 4
        for (int i = 0; i < NI; i += 4) {
            const float4 a  = *(const float4*)(inrow + i);
            const float4 w0 = *(const float4*)&Wt[(i + 0) * 64 + hq * 4];
            const float4 w1 = *(const float4*)&Wt[(i + 1) * 64 + hq * 4];
            const float4 w2 = *(const float4*)&Wt[(i + 2) * 64 + hq * 4];
            const float4 w3 = *(const float4*)&Wt[(i + 3) * 64 + hq * 4];
            ax += a.x * w0.x + a.y * w1.x + a.z * w2.x + a.w * w3.x;
            ay += a.x * w0.y + a.y * w1.y + a.z * w2.y + a.w * w3.y;
            az += a.x * w0.z + a.y * w1.z + a.z * w2.z + a.w * w3.z;
            aw += a.x * w0.w + a.y * w1.w + a.z * w2.w + a.w * w3.w;
        }
        float4 o = make_float4(ax + bias.x, ay + bias.y, az + bias.z, aw + bias.w);
        *(float4*)&out[row * NH + hbase + hq * 4] = o;
    }
}

__device__ __forceinline__ float tanh_fast(float x) {
    x = fminf(15.f, fmaxf(-15.f, x));
    const float ex = __expf(-2.f * x);
    return __fdividef(1.f - ex, 1.f + ex);
}

// ---------------------------------------------------------------------------
// Kernel 2: persistent recurrent scan. 128 WGs x 512 threads.
//   grp = bid & 15 (batch group; the group's 8 WGs share bid%8 -> same XCD
//   under round-robin dispatch — perf heuristic only), hgrp = bid >> 4.
// W_hh slice is LDS-resident f32 (512x64 = 128 KiB, loaded once) — no
// per-step weight traffic through global/scratch. y exchanged through global
// with agent-scope atomic stores + release-counter/acquire-fence barrier.
// y staged to LDS each step (one coalesced float4/thread), read back as
// wave-uniform broadcasts. part-reduce buffer aliases the y staging buffer
// (separated by __syncthreads). Threads tid>=256 compute redundant copies
// (stores gated) so the GEMM k-split keeps all 8 waves busy.
// ---------------------------------------------------------------------------
__global__ __launch_bounds__(512, 2) void horn_recurrent_kernel(
    const float* __restrict__ W_hh, const float* __restrict__ b_hh,
    const float* __restrict__ alpha, const float* __restrict__ omega,
    const float* __restrict__ gamma, const float* __restrict__ v,
    float* __restrict__ out, float* __restrict__ ybuf,
    unsigned* __restrict__ counters)
{
    __shared__ float Wl[NH][HPW];          // 128 KiB, [k][h-slice]
    __shared__ float ystage[BPG * NH];     // 8 KiB; aliased as part[] after GEMM

    float* y_lds = ystage;
    float (*part)[BPG][HPW] = (float (*)[BPG][HPW])ystage;  // [GSIZE][BPG][HPW]

    const int tid   = threadIdx.x;
    const int grp   = blockIdx.x & 15;   // batch group
    const int hgrp  = blockIdx.x >> 4;   // hidden slice
    const int bbase = grp * BPG;
    const int hbase = hgrp * HPW;

    const int kgrp = tid >> 6;               // 0..7 (k-split, one wave each)
    const int hk   = tid & 63;               // h within slice
    const int b2   = (tid >> 6) & (BPG - 1); // 0..3 (update mapping, 2x redundant)
    const int h2   = tid & 63;
    const int hg   = hbase + h2;

    // ---- W slice -> LDS (once). Coalesced: lanes hk consecutive. ----
    for (int k = kgrp; k < NH; k += GSIZE)
        Wl[k][hk] = W_hh[(size_t)k * NH + hbase + hk];

    const float bhh_r = b_hh[hg];
    const float al_r  = alpha[hg];
    const float omv   = omega[hg];
    const float om2_r = omv * omv;
    const float g2_r  = 2.0f * gamma[hg];
    const float v_r   = v[hg];
    const float gain  = 0.04419417382415922f;   // 1/sqrt(512)
    const float hdt   = 0.1f;

    unsigned* cnt = counters + grp * 64;   // 256 B spacing per group

    float x = 0.f, y = 0.f;
    __syncthreads();   // Wl ready

    for (int t = 0; t < T_STEPS; ++t) {
        // external input for this (b,h): issued now, consumed ~2k cycles later
        const size_t eidx = ((size_t)t * NB + bbase + b2) * NH + hg;
        const float e = out[eidx];

        // stage y(t) group slice (BPG x 512 = 8 KiB): 1 coalesced float4/thread
        {
            const float* src = ybuf + (size_t)(t & 1) * NB * NH + (size_t)bbase * NH;
            const int fo = tid * 4;
            *(float4*)(y_lds + fo) = *(const float4*)(src + fo);
        }
        __syncthreads();

        // GEMM: acc[b] = sum over this wave's 64 k of y[b][k]*W[k][hk]
        float acc[BPG];
        #pragma unroll
        for (int b = 0; b < BPG; ++b) acc[b] = 0.f;
        const int kb = kgrp * 64;
        #pragma unroll
        for (int q = 0; q < 16; ++q) {
            const float w0 = Wl[kb + q * 4 + 0][hk];
            const float w1 = Wl[kb + q * 4 + 1][hk];
            const float w2 = Wl[kb + q * 4 + 2][hk];
            const float w3 = Wl[kb + q * 4 + 3][hk];
            #pragma unroll
            for (int b = 0; b < BPG; ++b) {
                const float4 yv = *(const float4*)&y_lds[b * NH + kb + q * 4];
                acc[b] = fmaf(yv.w, w3, fmaf(yv.z, w2,
                         fmaf(yv.y, w1, fmaf(yv.x, w0, acc[b]))));
            }
        }
        __syncthreads();   // all y_lds reads done before part overwrites it

        #pragma unroll
        for (int b = 0; b < BPG; ++b) part[kgrp][b][hk] = acc[b];
        __syncthreads();

        // reduce over k-groups + bias
        float rec = bhh_r;
        #pragma unroll
        for (int g = 0; g < GSIZE; ++g) rec += part[g][b2][h2];

        // elementwise update (reference order)
        const float inp  = e + gain * (rec + v_r * x);
        const float ynew = y + hdt * (al_r * tanh_fast(inp) - om2_r * x - g2_r * y);
        const float xnew = x + hdt * ynew;
        x = xnew; y = ynew;

        // stores gated to the first copy (tid<256); agent-scope y store makes
        // cross-XCD visibility independent of dispatch placement
        if (tid < BPG * 64) {
            out[eidx] = xnew;
            __hip_atomic_store(
                ybuf + (size_t)((t + 1) & 1) * NB * NH + (size_t)(bbase + b2) * NH + hg,
                ynew, __ATOMIC_RELAXED, __HIP_MEMORY_SCOPE_AGENT);
        }

        if (t == T_STEPS - 1) break;

        // ---- group barrier (8 WGs) ----
        asm volatile("s_waitcnt vmcnt(0)" ::: "memory");  // my stores are at L2+
        __syncthreads();                                  // whole WG drained
        if (tid == 0) {
            __hip_atomic_fetch_add(cnt, 1u, __ATOMIC_RELEASE, __HIP_MEMORY_SCOPE_AGENT);
            const unsigned target = (unsigned)GSIZE * (unsigned)(t + 1);
            while (__hip_atomic_load(cnt, __ATOMIC_RELAXED, __HIP_MEMORY_SCOPE_AGENT) < target)
                __builtin_amdgcn_s_sleep(1);
            __builtin_amdgcn_fence(__ATOMIC_ACQUIRE, "agent");  // one L1/L2 inv
        }
        __syncthreads();
    }
}

// ---------------------------------------------------------------------------
extern "C" void kernel_launch(void* const* d_in, const int* in_sizes, int n_in,
                              void* d_out, int out_size, void* d_ws, size_t ws_size,
                              hipStream_t stream) {
    const float* inputs = (const float*)d_in[0];
    const float* W_ih   = (const float*)d_in[1];
    const float* b_ih   = (const float*)d_in[2];
    const float* W_hh   = (const float*)d_in[3];
    const float* b_hh   = (const float*)d_in[4];
    const float* alpha  = (const float*)d_in[5];
    const float* omega  = (const float*)d_in[6];
    const float* gamma  = (const float*)d_in[7];
    const float* v      = (const float*)d_in[8];
    float* out = (float*)d_out;

    unsigned* counters = (unsigned*)d_ws;
    float* ybuf = (float*)((char*)d_ws + WS_YBUF_OFF);

    // zero barrier counters + y buffer 0 (d_ws is re-poisoned every launch)
    hipMemsetAsync(d_ws, 0, WS_INIT_BYTES, stream);

    // ext = inputs @ W_ih + b_ih, written into d_out (overwritten step-by-step)
    ext_gemm_kernel<<<dim3(1024), dim3(256), 0, stream>>>(inputs, W_ih, b_ih, out);

    // sequential scan, persistent kernel: 128 WGs (16 groups x 8 slices)
    horn_recurrent_kernel<<<dim3(NGRP * GSIZE), dim3(512), 0, stream>>>(
        W_hh, b_hh, alpha, omega, gamma, v, out, ybuf, counters);
}